// Round 5
// baseline (834.558 us; speedup 1.0000x reference)
//
#include <hip/hip_runtime.h>

#define N_NODES 10000
#define N_EDGES 640000
#define D_FEAT 128

#define GRID 256
#define BLK  512
#define NTHREADS (GRID * BLK)          // 131072
#define NWAVES   (NTHREADS / 64)       // 2048

// ---------------------------------------------------------------------------
// ws int32-element offsets. [0, 10368) is memset to 0 before the kernel
// (counts + barrier slots + bsum + boff). Everything else is fully written
// before being read.
// ---------------------------------------------------------------------------
#define WS_COUNTS 0        // 10000 ints
#define WS_BAR    10016    // 8 barrier slots
#define WS_BSUM   10240    // 40
#define WS_BOFF   10304    // 40
#define WS_CTRL_INTS 10368 // memset range in ints
#define WS_START  16384    // 10001
#define WS_CURSOR 32768    // 10000
#define WS_SORTED 49152    // 640000
#define WS_AGG    689152   // float[10000*128]

// Device-scope grid barrier. Safe: grid=256 blocks, each CU holds >=1 block
// (LDS ~32B, VGPR<128), so all blocks are co-resident; every block reaches
// every barrier unconditionally.
__device__ __forceinline__ void gbar(int* slot) {
    __syncthreads();
    if (threadIdx.x == 0) {
        __threadfence();                       // release: publish phase writes
        atomicAdd(slot, 1);
        while (atomicAdd(slot, 0) < GRID) { }  // device-scope poll
    }
    __syncthreads();
    __threadfence();                           // acquire: invalidate stale L1
}

__global__ __launch_bounds__(BLK) void fused_kernel(
        const float4* __restrict__ edge_feat4,   // [640000*32]
        const float*  __restrict__ node_feat,    // [10000,128]
        const int4*   __restrict__ recv4,        // [160000]
        const float*  __restrict__ W,            // [256,128]
        const float*  __restrict__ bias,         // [128]
        float* __restrict__ out,                 // [10000,128]
        int* __restrict__ ws) {
    int* counts = ws + WS_COUNTS;
    int* bar    = ws + WS_BAR;
    int* bsum   = ws + WS_BSUM;
    int* boff   = ws + WS_BOFF;
    int* startp = ws + WS_START;
    int* cursor = ws + WS_CURSOR;
    int* sorted = ws + WS_SORTED;
    float* agg  = (float*)(ws + WS_AGG);

    const int tid  = threadIdx.x;
    const int bid  = blockIdx.x;
    const int gtid = bid * BLK + tid;

    __shared__ int s_wsum[8];

    // ---- P1: histogram of recv ------------------------------------------
    for (int i = gtid; i < N_EDGES / 4; i += NTHREADS) {
        const int4 r = recv4[i];
        atomicAdd(&counts[r.x], 1);
        atomicAdd(&counts[r.y], 1);
        atomicAdd(&counts[r.z], 1);
        atomicAdd(&counts[r.w], 1);
    }
    gbar(&bar[0]);

    // ---- P2a: per-block-of-256 sums (40 groups) -------------------------
    if (bid < 40 && tid < 256) {
        const int idx = bid * 256 + tid;
        int x = (idx < N_NODES) ? counts[idx] : 0;
        #pragma unroll
        for (int off = 32; off >= 1; off >>= 1) x += __shfl_down(x, off, 64);
        if ((tid & 63) == 0) s_wsum[tid >> 6] = x;
    }
    __syncthreads();
    if (bid < 40 && tid == 0)
        bsum[bid] = s_wsum[0] + s_wsum[1] + s_wsum[2] + s_wsum[3];
    gbar(&bar[1]);

    // ---- P2b: scan the 40 group sums ------------------------------------
    if (bid == 0 && tid < 64) {
        const int v = (tid < 40) ? bsum[tid] : 0;
        int x = v;
        #pragma unroll
        for (int off = 1; off < 64; off <<= 1) {
            int t = __shfl_up(x, off, 64);
            if (tid >= off) x += t;
        }
        if (tid < 40) boff[tid] = x - v;
        if (tid == 0) startp[N_NODES] = N_EDGES;
    }
    gbar(&bar[2]);

    // ---- P2c: final exclusive scan -> start[], cursor[] -----------------
    int p2_x = 0, p2_v = 0, p2_idx = -1;
    if (bid < 40 && tid < 256) {
        p2_idx = bid * 256 + tid;
        p2_v = (p2_idx < N_NODES) ? counts[p2_idx] : 0;
        p2_x = p2_v;
        #pragma unroll
        for (int off = 1; off < 64; off <<= 1) {
            int t = __shfl_up(p2_x, off, 64);
            if ((tid & 63) >= off) p2_x += t;
        }
        if ((tid & 63) == 63) s_wsum[4 + (tid >> 6)] = p2_x;
    }
    __syncthreads();
    if (bid < 40 && tid < 256 && p2_idx < N_NODES) {
        const int wave = tid >> 6;
        int woff = 0;
        #pragma unroll
        for (int k = 0; k < 3; ++k) woff += (k < wave) ? s_wsum[4 + k] : 0;
        const int excl = boff[bid] + woff + p2_x - p2_v;
        startp[p2_idx] = excl;
        cursor[p2_idx] = excl;
    }
    gbar(&bar[3]);

    // ---- P3: bucket edge ids by receiver --------------------------------
    for (int i = gtid; i < N_EDGES / 4; i += NTHREADS) {
        const int4 r = recv4[i];
        const int e = i * 4;
        sorted[atomicAdd(&cursor[r.x], 1)] = e + 0;
        sorted[atomicAdd(&cursor[r.y], 1)] = e + 1;
        sorted[atomicAdd(&cursor[r.z], 1)] = e + 2;
        sorted[atomicAdd(&cursor[r.w], 1)] = e + 3;
    }
    gbar(&bar[4]);

    // ---- P4: gather-sum, one wave per node ------------------------------
    // lane = 2 row-halves x 32 float4-chunks; unroll-4 rows in flight.
    {
        const int wid  = gtid >> 6;
        const int lane = tid & 63;
        const int half = lane >> 5;
        const int l    = lane & 31;
        for (int n = wid; n < N_NODES; n += NWAVES) {
            const int s = startp[n];
            const int e = startp[n + 1];
            float4 acc = {0.f, 0.f, 0.f, 0.f};
            int i = s + half;
            for (; i + 6 < e; i += 8) {
                const int e0 = sorted[i];
                const int e1 = sorted[i + 2];
                const int e2 = sorted[i + 4];
                const int e3 = sorted[i + 6];
                const float4 v0 = edge_feat4[(long)e0 * 32 + l];
                const float4 v1 = edge_feat4[(long)e1 * 32 + l];
                const float4 v2 = edge_feat4[(long)e2 * 32 + l];
                const float4 v3 = edge_feat4[(long)e3 * 32 + l];
                acc.x += (v0.x + v1.x) + (v2.x + v3.x);
                acc.y += (v0.y + v1.y) + (v2.y + v3.y);
                acc.z += (v0.z + v1.z) + (v2.z + v3.z);
                acc.w += (v0.w + v1.w) + (v2.w + v3.w);
            }
            for (; i < e; i += 2) {
                const float4 v = edge_feat4[(long)sorted[i] * 32 + l];
                acc.x += v.x; acc.y += v.y; acc.z += v.z; acc.w += v.w;
            }
            float4 o;
            o.x = acc.x + __shfl(acc.x, lane + 32, 64);
            o.y = acc.y + __shfl(acc.y, lane + 32, 64);
            o.z = acc.z + __shfl(acc.z, lane + 32, 64);
            o.w = acc.w + __shfl(acc.w, lane + 32, 64);
            if (half == 0)
                ((float4*)agg)[(long)n * 32 + l] = o;
        }
    }
    gbar(&bar[5]);

    // ---- P5: GEMM, LDS-free. out = [node||agg] @ W + b ------------------
    // 314 tiles of 64x64; each block's two 256-thread halves take one tile
    // each (blocks 0..156). Thread = 4 rows x 4 cols; A rows read row-major
    // (float4 per 4 k), W stays L2-hot (128 KB).
    if (bid < 157) {
        const int h  = tid >> 8;
        const int t  = tid & 255;
        const int tt = bid * 2 + h;           // 0..313
        const int m0 = (tt >> 1) * 64;
        const int n0 = (tt & 1) * 64;
        const int tx = t & 15;
        const int ty = t >> 4;
        int row[4];
        #pragma unroll
        for (int i2 = 0; i2 < 4; ++i2) {
            int r = m0 + ty * 4 + i2;
            row[i2] = (r < N_NODES) ? r : (N_NODES - 1);
        }
        const float* Wn = W + n0 + tx * 4;
        float4 acc[4] = {};

        #pragma unroll 2
        for (int k = 0; k < D_FEAT; k += 4) {
            const float4 b0 = *(const float4*)(Wn + (long)(k + 0) * D_FEAT);
            const float4 b1 = *(const float4*)(Wn + (long)(k + 1) * D_FEAT);
            const float4 b2 = *(const float4*)(Wn + (long)(k + 2) * D_FEAT);
            const float4 b3 = *(const float4*)(Wn + (long)(k + 3) * D_FEAT);
            #pragma unroll
            for (int i2 = 0; i2 < 4; ++i2) {
                const float4 a = *(const float4*)(node_feat + (long)row[i2] * D_FEAT + k);
                acc[i2].x += a.x * b0.x + a.y * b1.x + a.z * b2.x + a.w * b3.x;
                acc[i2].y += a.x * b0.y + a.y * b1.y + a.z * b2.y + a.w * b3.y;
                acc[i2].z += a.x * b0.z + a.y * b1.z + a.z * b2.z + a.w * b3.z;
                acc[i2].w += a.x * b0.w + a.y * b1.w + a.z * b2.w + a.w * b3.w;
            }
        }
        const float* W2 = Wn + (long)D_FEAT * D_FEAT;
        #pragma unroll 2
        for (int k = 0; k < D_FEAT; k += 4) {
            const float4 b0 = *(const float4*)(W2 + (long)(k + 0) * D_FEAT);
            const float4 b1 = *(const float4*)(W2 + (long)(k + 1) * D_FEAT);
            const float4 b2 = *(const float4*)(W2 + (long)(k + 2) * D_FEAT);
            const float4 b3 = *(const float4*)(W2 + (long)(k + 3) * D_FEAT);
            #pragma unroll
            for (int i2 = 0; i2 < 4; ++i2) {
                const float4 a = *(const float4*)(agg + (long)row[i2] * D_FEAT + k);
                acc[i2].x += a.x * b0.x + a.y * b1.x + a.z * b2.x + a.w * b3.x;
                acc[i2].y += a.x * b0.y + a.y * b1.y + a.z * b2.y + a.w * b3.y;
                acc[i2].z += a.x * b0.z + a.y * b1.z + a.z * b2.z + a.w * b3.z;
                acc[i2].w += a.x * b0.w + a.y * b1.w + a.z * b2.w + a.w * b3.w;
            }
        }

        const float4 bb = *(const float4*)(bias + n0 + tx * 4);
        #pragma unroll
        for (int i2 = 0; i2 < 4; ++i2) {
            const int r = m0 + ty * 4 + i2;
            if (r < N_NODES) {
                float4 o;
                o.x = acc[i2].x + bb.x;
                o.y = acc[i2].y + bb.y;
                o.z = acc[i2].z + bb.z;
                o.w = acc[i2].w + bb.w;
                *(float4*)(out + (long)r * D_FEAT + n0 + tx * 4) = o;
            }
        }
    }
}

// ---------------------------------------------------------------------------
extern "C" void kernel_launch(void* const* d_in, const int* in_sizes, int n_in,
                              void* d_out, int out_size, void* d_ws, size_t ws_size,
                              hipStream_t stream) {
    const float* edge_feat = (const float*)d_in[0];
    const float* node_feat = (const float*)d_in[1];
    const int*   recv      = (const int*)d_in[2];
    const float* W         = (const float*)d_in[3];
    const float* b         = (const float*)d_in[4];
    float* out = (float*)d_out;

    // zero counts + barrier slots + bsum + boff in one async memset
    hipMemsetAsync(d_ws, 0, (size_t)WS_CTRL_INTS * sizeof(int), stream);

    fused_kernel<<<GRID, BLK, 0, stream>>>(
        (const float4*)edge_feat, node_feat, (const int4*)recv,
        W, b, out, (int*)d_ws);
}

// Round 6
// 702.275 us; speedup vs baseline: 1.1884x; 1.1884x over previous
//
#include <hip/hip_runtime.h>

#define N_NODES 10000
#define N_EDGES 640000
#define D_FEAT 128

#define SGRID 256
#define SBLK  512
#define SNTHREADS (SGRID * SBLK)

// ---------------------------------------------------------------------------
// ws int32-element offsets. [0, WS_CTRL_INTS) is memset to 0 before launch.
// ---------------------------------------------------------------------------
#define WS_COUNTS 0        // 10000 ints
#define WS_BAR    10016    // 8 barrier slots
#define WS_BSUM   10240    // 40
#define WS_BOFF   10304    // 40
#define WS_CTRL_INTS 10368
#define WS_START  16384    // 10001
#define WS_CURSOR 32768    // 10000
#define WS_SORTED 49152    // 640000
#define WS_AGG    689152   // float[10000*128]

// Device-scope grid barrier. Grid=256 blocks of 8 waves @ ~60 VGPR -> worst
// case capacity >= 4 blocks/CU, so 256 blocks are always co-resident.
__device__ __forceinline__ void gbar(int* slot) {
    __syncthreads();
    if (threadIdx.x == 0) {
        __threadfence();
        atomicAdd(slot, 1);
        while (atomicAdd(slot, 0) < SGRID) { }
    }
    __syncthreads();
    __threadfence();
}

// ---------------------------------------------------------------------------
// Setup: histogram -> 3-phase exclusive scan -> bucket edge ids.
// All phases operate on ~2.6 MB of index data (L2-resident); they are
// atomic-throughput-bound, not latency-hiding-bound, so 8 waves/CU is fine.
// ---------------------------------------------------------------------------
__global__ __launch_bounds__(SBLK) void setup_kernel(
        const int4* __restrict__ recv4,
        int* __restrict__ ws) {
    int* counts = ws + WS_COUNTS;
    int* bar    = ws + WS_BAR;
    int* bsum   = ws + WS_BSUM;
    int* boff   = ws + WS_BOFF;
    int* startp = ws + WS_START;
    int* cursor = ws + WS_CURSOR;
    int* sorted = ws + WS_SORTED;

    const int tid  = threadIdx.x;
    const int bid  = blockIdx.x;
    const int gtid = bid * SBLK + tid;

    __shared__ int s_wsum[8];

    // ---- P1: histogram ---------------------------------------------------
    for (int i = gtid; i < N_EDGES / 4; i += SNTHREADS) {
        const int4 r = recv4[i];
        atomicAdd(&counts[r.x], 1);
        atomicAdd(&counts[r.y], 1);
        atomicAdd(&counts[r.z], 1);
        atomicAdd(&counts[r.w], 1);
    }
    gbar(&bar[0]);

    // ---- P2a: 40 group sums of 256 --------------------------------------
    if (bid < 40 && tid < 256) {
        const int idx = bid * 256 + tid;
        int x = (idx < N_NODES) ? counts[idx] : 0;
        #pragma unroll
        for (int off = 32; off >= 1; off >>= 1) x += __shfl_down(x, off, 64);
        if ((tid & 63) == 0) s_wsum[tid >> 6] = x;
    }
    __syncthreads();
    if (bid < 40 && tid == 0)
        bsum[bid] = s_wsum[0] + s_wsum[1] + s_wsum[2] + s_wsum[3];
    gbar(&bar[1]);

    // ---- P2b: scan 40 group sums ----------------------------------------
    if (bid == 0 && tid < 64) {
        const int v = (tid < 40) ? bsum[tid] : 0;
        int x = v;
        #pragma unroll
        for (int off = 1; off < 64; off <<= 1) {
            int t = __shfl_up(x, off, 64);
            if (tid >= off) x += t;
        }
        if (tid < 40) boff[tid] = x - v;
        if (tid == 0) startp[N_NODES] = N_EDGES;
    }
    gbar(&bar[2]);

    // ---- P2c: final exclusive scan -> start[], cursor[] -----------------
    int p2_x = 0, p2_v = 0, p2_idx = -1;
    if (bid < 40 && tid < 256) {
        p2_idx = bid * 256 + tid;
        p2_v = (p2_idx < N_NODES) ? counts[p2_idx] : 0;
        p2_x = p2_v;
        #pragma unroll
        for (int off = 1; off < 64; off <<= 1) {
            int t = __shfl_up(p2_x, off, 64);
            if ((tid & 63) >= off) p2_x += t;
        }
        if ((tid & 63) == 63) s_wsum[4 + (tid >> 6)] = p2_x;
    }
    __syncthreads();
    if (bid < 40 && tid < 256 && p2_idx < N_NODES) {
        const int wave = tid >> 6;
        int woff = 0;
        #pragma unroll
        for (int k = 0; k < 3; ++k) woff += (k < wave) ? s_wsum[4 + k] : 0;
        const int excl = boff[bid] + woff + p2_x - p2_v;
        startp[p2_idx] = excl;
        cursor[p2_idx] = excl;
    }
    gbar(&bar[3]);

    // ---- P3: bucket edge ids by receiver --------------------------------
    for (int i = gtid; i < N_EDGES / 4; i += SNTHREADS) {
        const int4 r = recv4[i];
        const int e = i * 4;
        sorted[atomicAdd(&cursor[r.x], 1)] = e + 0;
        sorted[atomicAdd(&cursor[r.y], 1)] = e + 1;
        sorted[atomicAdd(&cursor[r.z], 1)] = e + 2;
        sorted[atomicAdd(&cursor[r.w], 1)] = e + 3;
    }
}

// ---------------------------------------------------------------------------
// Gather-sum: one 512-thread block per node (oversubscribed: 10000 blocks ->
// full occupancy for latency hiding). 16 row groups of 32 lanes; lane reads
// a float4 chunk; next index prefetched -> 2-deep pipeline. No atomics.
// ---------------------------------------------------------------------------
#define GW 16
__global__ __launch_bounds__(512) void gather_kernel(
        const float4* __restrict__ edge_feat4,
        const int* __restrict__ sorted_eid,
        const int* __restrict__ start,
        float4* __restrict__ agg4) {
    __shared__ float4 red[GW][32];
    const int n   = blockIdx.x;
    const int tid = threadIdx.x;
    const int l   = tid & 31;
    const int w   = tid >> 5;
    const int s = start[n];
    const int e = start[n + 1];
    float4 acc = {0.f, 0.f, 0.f, 0.f};
    int i = s + w;
    if (i < e) {
        int eid = sorted_eid[i];
        while (true) {
            const int inext = i + GW;
            const int eid_next = (inext < e) ? sorted_eid[inext] : 0;
            const float4 v = edge_feat4[(long)eid * 32 + l];
            acc.x += v.x; acc.y += v.y; acc.z += v.z; acc.w += v.w;
            i = inext;
            if (i >= e) break;
            eid = eid_next;
        }
    }
    red[w][l] = acc;
    __syncthreads();
    if (w == 0) {
        float4 r = red[0][l];
        #pragma unroll
        for (int g = 1; g < GW; ++g) {
            const float4 t = red[g][l];
            r.x += t.x; r.y += t.y; r.z += t.z; r.w += t.w;
        }
        agg4[(long)n * 32 + l] = r;
    }
}

// ---------------------------------------------------------------------------
// Register-tiled GEMM: out[10000,128] = [node||agg][10000,256] @ W + b
// BM=64 BN=64 BK=32; 256 threads, 4x4 acc each.
// ---------------------------------------------------------------------------
__global__ __launch_bounds__(256) void gemm_kernel(
        const float* __restrict__ node_feat,
        const float* __restrict__ agg,
        const float* __restrict__ W,
        const float* __restrict__ b,
        float* __restrict__ out) {
    __shared__ __align__(16) float As[32][68];
    __shared__ __align__(16) float Bs[32][64];
    const int tid = threadIdx.x;
    const int tx = tid & 15;
    const int ty = tid >> 4;
    const int m0 = blockIdx.x * 64;
    const int n0 = blockIdx.y * 64;

    float acc[4][4] = {};

    for (int kt = 0; kt < 2 * D_FEAT; kt += 32) {
        const float* src = (kt < D_FEAT) ? (node_feat + kt) : (agg + (kt - D_FEAT));
        {   // A tile: 64 rows x 32 cols -> As[k][m]
            const int r  = tid >> 3;
            const int c4 = tid & 7;
            #pragma unroll
            for (int p = 0; p < 2; ++p) {
                int row = m0 + p * 32 + r;
                row = (row < N_NODES) ? row : (N_NODES - 1);
                const float4 a4 = *(const float4*)(src + (long)row * D_FEAT + c4 * 4);
                As[c4 * 4 + 0][p * 32 + r] = a4.x;
                As[c4 * 4 + 1][p * 32 + r] = a4.y;
                As[c4 * 4 + 2][p * 32 + r] = a4.z;
                As[c4 * 4 + 3][p * 32 + r] = a4.w;
            }
        }
        {   // B tile: 32 rows x 64 cols -> Bs[k][n]
            const int r  = tid >> 4;
            const int c4 = tid & 15;
            #pragma unroll
            for (int p = 0; p < 2; ++p) {
                const int row = kt + p * 16 + r;
                *(float4*)&Bs[p * 16 + r][c4 * 4] =
                    *(const float4*)(W + (long)row * D_FEAT + n0 + c4 * 4);
            }
        }
        __syncthreads();
        #pragma unroll
        for (int kk = 0; kk < 32; ++kk) {
            const float4 a4 = *(const float4*)&As[kk][ty * 4];
            const float4 b4 = *(const float4*)&Bs[kk][tx * 4];
            acc[0][0] += a4.x * b4.x; acc[0][1] += a4.x * b4.y;
            acc[0][2] += a4.x * b4.z; acc[0][3] += a4.x * b4.w;
            acc[1][0] += a4.y * b4.x; acc[1][1] += a4.y * b4.y;
            acc[1][2] += a4.y * b4.z; acc[1][3] += a4.y * b4.w;
            acc[2][0] += a4.z * b4.x; acc[2][1] += a4.z * b4.y;
            acc[2][2] += a4.z * b4.z; acc[2][3] += a4.z * b4.w;
            acc[3][0] += a4.w * b4.x; acc[3][1] += a4.w * b4.y;
            acc[3][2] += a4.w * b4.z; acc[3][3] += a4.w * b4.w;
        }
        __syncthreads();
    }

    const float4 bias = *(const float4*)(b + n0 + tx * 4);
    #pragma unroll
    for (int i2 = 0; i2 < 4; ++i2) {
        const int row = m0 + ty * 4 + i2;
        if (row < N_NODES) {
            float4 o;
            o.x = acc[i2][0] + bias.x;
            o.y = acc[i2][1] + bias.y;
            o.z = acc[i2][2] + bias.z;
            o.w = acc[i2][3] + bias.w;
            *(float4*)(out + (long)row * D_FEAT + n0 + tx * 4) = o;
        }
    }
}

// ---------------------------------------------------------------------------
extern "C" void kernel_launch(void* const* d_in, const int* in_sizes, int n_in,
                              void* d_out, int out_size, void* d_ws, size_t ws_size,
                              hipStream_t stream) {
    const float* edge_feat = (const float*)d_in[0];
    const float* node_feat = (const float*)d_in[1];
    const int*   recv      = (const int*)d_in[2];
    const float* W         = (const float*)d_in[3];
    const float* b         = (const float*)d_in[4];
    float* out = (float*)d_out;

    int* wsi    = (int*)d_ws;
    int* startp = wsi + WS_START;
    int* sorted = wsi + WS_SORTED;
    float* agg  = (float*)(wsi + WS_AGG);

    hipMemsetAsync(d_ws, 0, (size_t)WS_CTRL_INTS * sizeof(int), stream);

    setup_kernel<<<SGRID, SBLK, 0, stream>>>((const int4*)recv, (int*)d_ws);

    gather_kernel<<<N_NODES, 512, 0, stream>>>(
        (const float4*)edge_feat, sorted, startp, (float4*)agg);

    dim3 ggrid((N_NODES + 63) / 64, D_FEAT / 64);
    gemm_kernel<<<ggrid, 256, 0, stream>>>(node_feat, agg, W, b, out);
}

// Round 7
// 488.011 us; speedup vs baseline: 1.7101x; 1.4391x over previous
//
#include <hip/hip_runtime.h>

#define N_NODES 10000
#define N_EDGES 640000
#define D_FEAT 128

// ---------------------------------------------------------------------------
// Privatized counting sort: HB blocks each own a contiguous slice of edges.
// ---------------------------------------------------------------------------
#define HB   64                      // hist/reorder blocks
#define HBLK 1024
#define EPB  (N_EDGES / HB)          // 10000 edges per block
#define BCS  10016                   // bcnt row stride (ints)

// ws int32-element offsets (no memset needed: everything fully written
// before being read).
#define WS_BCNT   0                        // HB * BCS = 641024
#define WS_BSUM   641024                   // 40
#define WS_START  641088                   // 10001
#define WS_SORTED 651392                   // 640000
#define WS_AGG    1291392                  // float[10000*128]

// ---------------------------------------------------------------------------
// K1: per-block LDS histogram of this block's 10000-edge slice, dumped
// non-atomically to bcnt[bid][*]. No global atomics at all.
// ---------------------------------------------------------------------------
__global__ __launch_bounds__(HBLK) void hist_kernel(
        const int* __restrict__ recv, int* __restrict__ bcnt) {
    __shared__ int h[N_NODES];               // 40 KB
    for (int i = threadIdx.x; i < N_NODES; i += HBLK) h[i] = 0;
    __syncthreads();
    const int4* r4 = (const int4*)(recv + blockIdx.x * EPB);
    for (int i = threadIdx.x; i < EPB / 4; i += HBLK) {
        const int4 r = r4[i];
        atomicAdd(&h[r.x], 1);               // ds_add (LDS scope)
        atomicAdd(&h[r.y], 1);
        atomicAdd(&h[r.z], 1);
        atomicAdd(&h[r.w], 1);
    }
    __syncthreads();
    int* dst = bcnt + blockIdx.x * BCS;
    for (int i = threadIdx.x; i < N_NODES; i += HBLK) dst[i] = h[i];
}

// ---------------------------------------------------------------------------
// K2: node-parallel. For node n: exclusive prefix over the 64 block counts
// (written back in place), node total -> in-block exclusive scan -> partial
// start[] (block-local) + per-scan-block sums.
// ---------------------------------------------------------------------------
__global__ __launch_bounds__(256) void scan1_kernel(
        int* __restrict__ bcnt, int* __restrict__ start, int* __restrict__ bsum) {
    __shared__ int s_w[4];
    const int tid = threadIdx.x;
    const int n   = blockIdx.x * 256 + tid;
    const bool ok = (n < N_NODES);

    int tot = 0;
    if (ok) {
        int run = 0;
        #pragma unroll
        for (int b = 0; b < HB; ++b) {
            int* p = bcnt + b * BCS + n;     // coalesced across lanes
            const int c = *p;
            *p = run;                        // exclusive per-block offset
            run += c;
        }
        tot = run;
    }
    // in-block exclusive scan of tot over 256 threads
    const int lane = tid & 63;
    const int wave = tid >> 6;
    int x = tot;
    #pragma unroll
    for (int off = 1; off < 64; off <<= 1) {
        int t = __shfl_up(x, off, 64);
        if (lane >= off) x += t;
    }
    if (lane == 63) s_w[wave] = x;
    __syncthreads();
    int woff = 0;
    #pragma unroll
    for (int k = 0; k < 3; ++k) woff += (k < wave) ? s_w[k] : 0;
    if (ok) start[n] = woff + x - tot;       // block-local exclusive
    if (tid == 0) bsum[blockIdx.x] = s_w[0] + s_w[1] + s_w[2] + s_w[3];
}

// ---------------------------------------------------------------------------
// K3: add cross-block offsets into start[]. Each block scans the 40 bsums
// locally (40 ints -- trivial).
// ---------------------------------------------------------------------------
__global__ __launch_bounds__(256) void scan2_kernel(
        const int* __restrict__ bsum, int* __restrict__ start) {
    __shared__ int s_boff;
    const int tid = threadIdx.x;
    if (tid == 0) {
        int acc = 0;
        for (int k = 0; k < (int)blockIdx.x; ++k) acc += bsum[k];
        s_boff = acc;
        if (blockIdx.x == 0) start[N_NODES] = N_EDGES;
    }
    __syncthreads();
    const int n = blockIdx.x * 256 + tid;
    if (n < N_NODES) start[n] += s_boff;
}

// ---------------------------------------------------------------------------
// K4: reorder. Block bid re-reads its slice; absolute cursor for node n is
// start[n] + bcnt[bid][n] preloaded into LDS; rank via ds_add_rtn. The only
// global traffic: coalesced reads + 2.56 MB scattered 4B writes. No global
// atomics.
// ---------------------------------------------------------------------------
__global__ __launch_bounds__(HBLK) void reorder_kernel(
        const int* __restrict__ recv, const int* __restrict__ bcnt,
        const int* __restrict__ start, int* __restrict__ sorted) {
    __shared__ int cur[N_NODES];             // 40 KB
    const int* rel = bcnt + blockIdx.x * BCS;
    for (int i = threadIdx.x; i < N_NODES; i += HBLK)
        cur[i] = start[i] + rel[i];
    __syncthreads();
    const int ebase = blockIdx.x * EPB;
    const int4* r4 = (const int4*)(recv + ebase);
    for (int i = threadIdx.x; i < EPB / 4; i += HBLK) {
        const int4 r = r4[i];
        const int e = ebase + i * 4;
        sorted[atomicAdd(&cur[r.x], 1)] = e + 0;   // ds_add_rtn (LDS)
        sorted[atomicAdd(&cur[r.y], 1)] = e + 1;
        sorted[atomicAdd(&cur[r.z], 1)] = e + 2;
        sorted[atomicAdd(&cur[r.w], 1)] = e + 3;
    }
}

// ---------------------------------------------------------------------------
// K5: gather-sum, one 512-thread block per node (oversubscribed). 16 row
// groups of 32 lanes; float4 chunk per lane; 2-deep index prefetch.
// ---------------------------------------------------------------------------
#define GW 16
__global__ __launch_bounds__(512) void gather_kernel(
        const float4* __restrict__ edge_feat4,
        const int* __restrict__ sorted_eid,
        const int* __restrict__ start,
        float4* __restrict__ agg4) {
    __shared__ float4 red[GW][32];
    const int n   = blockIdx.x;
    const int tid = threadIdx.x;
    const int l   = tid & 31;
    const int w   = tid >> 5;
    const int s = start[n];
    const int e = start[n + 1];
    float4 acc = {0.f, 0.f, 0.f, 0.f};
    int i = s + w;
    if (i < e) {
        int eid = sorted_eid[i];
        while (true) {
            const int inext = i + GW;
            const int eid_next = (inext < e) ? sorted_eid[inext] : 0;
            const float4 v = edge_feat4[(long)eid * 32 + l];
            acc.x += v.x; acc.y += v.y; acc.z += v.z; acc.w += v.w;
            i = inext;
            if (i >= e) break;
            eid = eid_next;
        }
    }
    red[w][l] = acc;
    __syncthreads();
    if (w == 0) {
        float4 r = red[0][l];
        #pragma unroll
        for (int g = 1; g < GW; ++g) {
            const float4 t = red[g][l];
            r.x += t.x; r.y += t.y; r.z += t.z; r.w += t.w;
        }
        agg4[(long)n * 32 + l] = r;
    }
}

// ---------------------------------------------------------------------------
// K6: register-tiled GEMM: out[10000,128] = [node||agg][10000,256] @ W + b
// ---------------------------------------------------------------------------
__global__ __launch_bounds__(256) void gemm_kernel(
        const float* __restrict__ node_feat,
        const float* __restrict__ agg,
        const float* __restrict__ W,
        const float* __restrict__ b,
        float* __restrict__ out) {
    __shared__ __align__(16) float As[32][68];
    __shared__ __align__(16) float Bs[32][64];
    const int tid = threadIdx.x;
    const int tx = tid & 15;
    const int ty = tid >> 4;
    const int m0 = blockIdx.x * 64;
    const int n0 = blockIdx.y * 64;

    float acc[4][4] = {};

    for (int kt = 0; kt < 2 * D_FEAT; kt += 32) {
        const float* src = (kt < D_FEAT) ? (node_feat + kt) : (agg + (kt - D_FEAT));
        {   // A tile: 64 rows x 32 cols -> As[k][m]
            const int r  = tid >> 3;
            const int c4 = tid & 7;
            #pragma unroll
            for (int p = 0; p < 2; ++p) {
                int row = m0 + p * 32 + r;
                row = (row < N_NODES) ? row : (N_NODES - 1);
                const float4 a4 = *(const float4*)(src + (long)row * D_FEAT + c4 * 4);
                As[c4 * 4 + 0][p * 32 + r] = a4.x;
                As[c4 * 4 + 1][p * 32 + r] = a4.y;
                As[c4 * 4 + 2][p * 32 + r] = a4.z;
                As[c4 * 4 + 3][p * 32 + r] = a4.w;
            }
        }
        {   // B tile: 32 rows x 64 cols -> Bs[k][n]
            const int r  = tid >> 4;
            const int c4 = tid & 15;
            #pragma unroll
            for (int p = 0; p < 2; ++p) {
                const int row = kt + p * 16 + r;
                *(float4*)&Bs[p * 16 + r][c4 * 4] =
                    *(const float4*)(W + (long)row * D_FEAT + n0 + c4 * 4);
            }
        }
        __syncthreads();
        #pragma unroll
        for (int kk = 0; kk < 32; ++kk) {
            const float4 a4 = *(const float4*)&As[kk][ty * 4];
            const float4 b4 = *(const float4*)&Bs[kk][tx * 4];
            acc[0][0] += a4.x * b4.x; acc[0][1] += a4.x * b4.y;
            acc[0][2] += a4.x * b4.z; acc[0][3] += a4.x * b4.w;
            acc[1][0] += a4.y * b4.x; acc[1][1] += a4.y * b4.y;
            acc[1][2] += a4.y * b4.z; acc[1][3] += a4.y * b4.w;
            acc[2][0] += a4.z * b4.x; acc[2][1] += a4.z * b4.y;
            acc[2][2] += a4.z * b4.z; acc[2][3] += a4.z * b4.w;
            acc[3][0] += a4.w * b4.x; acc[3][1] += a4.w * b4.y;
            acc[3][2] += a4.w * b4.z; acc[3][3] += a4.w * b4.w;
        }
        __syncthreads();
    }

    const float4 bias = *(const float4*)(b + n0 + tx * 4);
    #pragma unroll
    for (int i2 = 0; i2 < 4; ++i2) {
        const int row = m0 + ty * 4 + i2;
        if (row < N_NODES) {
            float4 o;
            o.x = acc[i2][0] + bias.x;
            o.y = acc[i2][1] + bias.y;
            o.z = acc[i2][2] + bias.z;
            o.w = acc[i2][3] + bias.w;
            *(float4*)(out + (long)row * D_FEAT + n0 + tx * 4) = o;
        }
    }
}

// ---------------------------------------------------------------------------
extern "C" void kernel_launch(void* const* d_in, const int* in_sizes, int n_in,
                              void* d_out, int out_size, void* d_ws, size_t ws_size,
                              hipStream_t stream) {
    const float* edge_feat = (const float*)d_in[0];
    const float* node_feat = (const float*)d_in[1];
    const int*   recv      = (const int*)d_in[2];
    const float* W         = (const float*)d_in[3];
    const float* b         = (const float*)d_in[4];
    float* out = (float*)d_out;

    int* wsi    = (int*)d_ws;
    int* bcnt   = wsi + WS_BCNT;
    int* bsum   = wsi + WS_BSUM;
    int* startp = wsi + WS_START;
    int* sorted = wsi + WS_SORTED;
    float* agg  = (float*)(wsi + WS_AGG);

    hist_kernel<<<HB, HBLK, 0, stream>>>(recv, bcnt);
    scan1_kernel<<<(N_NODES + 255) / 256, 256, 0, stream>>>(bcnt, startp, bsum);
    scan2_kernel<<<(N_NODES + 255) / 256, 256, 0, stream>>>(bsum, startp);
    reorder_kernel<<<HB, HBLK, 0, stream>>>(recv, bcnt, startp, sorted);
    gather_kernel<<<N_NODES, 512, 0, stream>>>(
        (const float4*)edge_feat, sorted, startp, (float4*)agg);
    dim3 ggrid((N_NODES + 63) / 64, D_FEAT / 64);
    gemm_kernel<<<ggrid, 256, 0, stream>>>(node_feat, agg, W, b, out);
}